// Round 1
// baseline (284.900 us; speedup 1.0000x reference)
//
#include <hip/hip_runtime.h>
#include <hip/hip_bf16.h>

// Attention layer: B=2, S=2048, H=2048, NH=16, NKV=4, HD=128, N_REP=4
// Pipeline: cvt X->bf16; transpose weights (f32->bf16, N x K); fused QKV GEMM;
// RoPE; V transpose; causal flash attention (GQA); output-proj GEMM (f32 out).

typedef __bf16 bf16;
typedef __bf16 bf16x8 __attribute__((ext_vector_type(8)));
typedef __bf16 bf16x4 __attribute__((ext_vector_type(4)));
typedef float  f32x4  __attribute__((ext_vector_type(4)));

#define MFMA_BF16(a, b, c) __builtin_amdgcn_mfma_f32_16x16x32_bf16((a), (b), (c), 0, 0, 0)

// ------------------------------------------------------------------
// f32 -> bf16 elementwise (vectorized x4)
__global__ __launch_bounds__(256) void k_cvt_bf16(const float* __restrict__ in,
                                                  bf16* __restrict__ out, int n4) {
  int i = blockIdx.x * 256 + threadIdx.x;
  if (i < n4) {
    float4 v = ((const float4*)in)[i];
    bf16x4 o;
    o[0] = (bf16)v.x; o[1] = (bf16)v.y; o[2] = (bf16)v.z; o[3] = (bf16)v.w;
    ((bf16x4*)out)[i] = o;
  }
}

// ------------------------------------------------------------------
// W [Kd][N] f32  ->  Wt [N][Kd] bf16   (LDS tile transpose, pad 33)
__global__ __launch_bounds__(256) void k_transpose_w(const float* __restrict__ W,
                                                     bf16* __restrict__ Wt, int Kd, int N) {
  __shared__ float tile[32][33];
  int tx = threadIdx.x, ty = threadIdx.y;
  int kb = blockIdx.x * 32, nb = blockIdx.y * 32;
#pragma unroll
  for (int i = 0; i < 4; ++i)
    tile[ty + i * 8][tx] = W[(size_t)(kb + ty + i * 8) * N + nb + tx];
  __syncthreads();
#pragma unroll
  for (int i = 0; i < 4; ++i)
    Wt[(size_t)(nb + ty + i * 8) * Kd + kb + tx] = (bf16)tile[tx][ty + i * 8];
}

// ------------------------------------------------------------------
// V [4096][512] bf16 -> Vt [(b*4+kv)*128 + d][2048] bf16
__global__ __launch_bounds__(256) void k_transpose_v(const bf16* __restrict__ V,
                                                     bf16* __restrict__ Vt) {
  __shared__ bf16 tile[32][33];
  int tx = threadIdx.x, ty = threadIdx.y;
  int b = blockIdx.z;
  int sb = blockIdx.x * 32, cb = blockIdx.y * 32;
#pragma unroll
  for (int i = 0; i < 4; ++i)
    tile[ty + i * 8][tx] = V[(size_t)(b * 2048 + sb + ty + i * 8) * 512 + cb + tx];
  __syncthreads();
#pragma unroll
  for (int i = 0; i < 4; ++i)
    Vt[(size_t)(b * 512 + cb + ty + i * 8) * 2048 + sb + tx] = tile[tx][ty + i * 8];
}

// ------------------------------------------------------------------
// RoPE in-place on [4096][ncols] bf16. Pair (h*128+d, h*128+d+64), d<64.
__global__ __launch_bounds__(256) void k_rope(bf16* __restrict__ T,
                                              const float* __restrict__ cosb,
                                              const float* __restrict__ sinb, int ncols) {
  int i = blockIdx.x * 256 + threadIdx.x;
  int npr = ncols >> 1;             // pairs per row (power of 2)
  int row = i / npr;
  int p = i - row * npr;
  int h = p >> 6, d = p & 63;
  int c0 = h * 128 + d;
  size_t base = (size_t)row * ncols;
  int s = row & 2047;
  float q0 = (float)T[base + c0];
  float q1 = (float)T[base + c0 + 64];
  float vc0 = cosb[s * 128 + d],      vc1 = cosb[s * 128 + d + 64];
  float vs0 = sinb[s * 128 + d],      vs1 = sinb[s * 128 + d + 64];
  T[base + c0]      = (bf16)(q0 * vc0 - q1 * vs0);
  T[base + c0 + 64] = (bf16)(q1 * vc1 + q0 * vs1);
}

// ------------------------------------------------------------------
// GEMM block: C[128x128] = A[128xK] * Wt^T ; A,Wt row-major bf16 with rows of K.
// 4 waves, wave w does rows w*32..w*32+31 x all 128 cols. BK=64.
// LDS tiles [128 rows][64 k] bf16, XOR-swizzled per 16B chunk: byte ^= (row&7)<<4.
template <typename OUT>
__device__ void gemm_block(const bf16* __restrict__ A, const bf16* __restrict__ Bt,
                           OUT* __restrict__ C, int K, int ldc,
                           int rbase, int cbase, bf16* lds) {
  const int tid = threadIdx.x;
  const int lane = tid & 63, wid = tid >> 6;
  const int l15 = lane & 15, lg = lane >> 4;
  char* At = (char*)lds;              // [128][128B]
  char* Bti = (char*)(lds + 128 * 64);

  f32x4 acc[2][8];
#pragma unroll
  for (int i = 0; i < 2; ++i)
#pragma unroll
    for (int j = 0; j < 8; ++j)
#pragma unroll
      for (int r = 0; r < 4; ++r) acc[i][j][r] = 0.0f;

  for (int kb = 0; kb < K; kb += 64) {
    __syncthreads();
#pragma unroll
    for (int i = 0; i < 4; ++i) {
      int c = tid + i * 256;
      int r = c >> 3, cc = c & 7;
      const bf16* src = A + (size_t)(rbase + r) * K + kb + cc * 8;
      *(bf16x8*)(At + r * 128 + ((cc * 16) ^ ((r & 7) << 4))) = *(const bf16x8*)src;
    }
#pragma unroll
    for (int i = 0; i < 4; ++i) {
      int c = tid + i * 256;
      int r = c >> 3, cc = c & 7;
      const bf16* src = Bt + (size_t)(cbase + r) * K + kb + cc * 8;
      *(bf16x8*)(Bti + r * 128 + ((cc * 16) ^ ((r & 7) << 4))) = *(const bf16x8*)src;
    }
    __syncthreads();

#pragma unroll
    for (int ks = 0; ks < 2; ++ks) {
      const int kbyte = ks * 64 + lg * 16;
      bf16x8 a[2], b[8];
#pragma unroll
      for (int rf = 0; rf < 2; ++rf) {
        int r = wid * 32 + rf * 16 + l15;
        a[rf] = *(const bf16x8*)(At + r * 128 + (kbyte ^ ((r & 7) << 4)));
      }
#pragma unroll
      for (int nf = 0; nf < 8; ++nf) {
        int n = nf * 16 + l15;
        b[nf] = *(const bf16x8*)(Bti + n * 128 + (kbyte ^ ((n & 7) << 4)));
      }
#pragma unroll
      for (int rf = 0; rf < 2; ++rf)
#pragma unroll
        for (int nf = 0; nf < 8; ++nf)
          acc[rf][nf] = MFMA_BF16(a[rf], b[nf], acc[rf][nf]);
    }
  }

#pragma unroll
  for (int rf = 0; rf < 2; ++rf)
#pragma unroll
    for (int nf = 0; nf < 8; ++nf)
#pragma unroll
      for (int r = 0; r < 4; ++r) {
        int row = rbase + wid * 32 + rf * 16 + lg * 4 + r;
        int col = cbase + nf * 16 + l15;
        C[(size_t)row * ldc + col] = (OUT)acc[rf][nf][r];
      }
}

// Fused QKV projection: grid (32, 24). y<16 -> Q, 16..19 -> K, 20..23 -> V.
__global__ __launch_bounds__(256, 2) void k_gemm_qkv(const bf16* __restrict__ X,
                                                     const bf16* __restrict__ Wtq,
                                                     const bf16* __restrict__ Wtk,
                                                     const bf16* __restrict__ Wtv,
                                                     bf16* __restrict__ Q,
                                                     bf16* __restrict__ Ko,
                                                     bf16* __restrict__ Vo) {
  __shared__ alignas(16) bf16 lds[2 * 128 * 64];
  int nb = blockIdx.y;
  int rbase = blockIdx.x * 128;
  const bf16* Bt; bf16* C; int ldc, cbase;
  if (nb < 16)      { Bt = Wtq; C = Q;  ldc = 2048; cbase = nb * 128; }
  else if (nb < 20) { Bt = Wtk; C = Ko; ldc = 512;  cbase = (nb - 16) * 128; }
  else              { Bt = Wtv; C = Vo; ldc = 512;  cbase = (nb - 20) * 128; }
  gemm_block<bf16>(X, Bt, C, 2048, ldc, rbase, cbase, lds);
}

// Output projection: AO[4096][2048] bf16 x Wto -> d_out f32
__global__ __launch_bounds__(256, 2) void k_gemm_o(const bf16* __restrict__ AO,
                                                   const bf16* __restrict__ Wto,
                                                   float* __restrict__ Out) {
  __shared__ alignas(16) bf16 lds[2 * 128 * 64];
  gemm_block<float>(AO, Wto, Out, 2048, 2048, blockIdx.x * 128, blockIdx.y * 128, lds);
}

// ------------------------------------------------------------------
// Causal flash attention, GQA. grid (S/128, NH, B), 256 threads (4 waves x 32 q-rows).
// K tile [64][128d] and Vt tile [128d][64s] staged in swizzled LDS; P via per-wave LDS.
__global__ __launch_bounds__(256, 2) void k_fattn(const bf16* __restrict__ Qg,
                                                  const bf16* __restrict__ Kg,
                                                  const bf16* __restrict__ Vtg,
                                                  bf16* __restrict__ AO) {
  __shared__ alignas(16) char sm[49152];
  char* Kt  = sm;                                        // [64][256B]
  char* Vtt = sm + 16384;                                // [128][128B]
  char* Pl  = sm + 32768 + ((threadIdx.x >> 6) << 12);   // per-wave [32][128B]
  const int lane = threadIdx.x & 63, wid = threadIdx.x >> 6;
  const int l15 = lane & 15, lg = lane >> 4;
  const int b = blockIdx.z, h = blockIdx.y, kv = h >> 2;
  const int qbase = blockIdx.x * 128;
  const int qr = qbase + wid * 32;

  // Q fragments (held in registers for the whole kernel)
  bf16x8 qf[2][4];
#pragma unroll
  for (int rf = 0; rf < 2; ++rf)
#pragma unroll
    for (int kf = 0; kf < 4; ++kf) {
      size_t idx = (size_t)(b * 2048 + qr + rf * 16 + l15) * 2048 + h * 128 + kf * 32 + lg * 8;
      qf[rf][kf] = *(const bf16x8*)(Qg + idx);
    }

  f32x4 o[2][8];
#pragma unroll
  for (int i = 0; i < 2; ++i)
#pragma unroll
    for (int j = 0; j < 8; ++j)
#pragma unroll
      for (int r = 0; r < 4; ++r) o[i][j][r] = 0.0f;

  float mrun[2][4], lrun[2][4];
#pragma unroll
  for (int rf = 0; rf < 2; ++rf)
#pragma unroll
    for (int r = 0; r < 4; ++r) { mrun[rf][r] = -1e30f; lrun[rf][r] = 0.0f; }

  const float scale = 0.08838834764831845f;  // 1/sqrt(128)
  const float L2E = 1.4426950408889634f;
  const int kend = qbase + 128;

  for (int kb = 0; kb < kend; kb += 64) {
    __syncthreads();
    // stage K tile (64 rows x 256B), swizzled
#pragma unroll
    for (int i = 0; i < 4; ++i) {
      int c = threadIdx.x + i * 256;
      int r = c >> 4, cc = c & 15;
      const bf16* src = Kg + (size_t)(b * 2048 + kb + r) * 512 + kv * 128 + cc * 8;
      *(bf16x8*)(Kt + r * 256 + ((cc * 16) ^ ((r & 7) << 4))) = *(const bf16x8*)src;
    }
    // stage Vt tile (128 rows x 128B), swizzled
#pragma unroll
    for (int i = 0; i < 4; ++i) {
      int c = threadIdx.x + i * 256;
      int r = c >> 3, cc = c & 7;
      const bf16* src = Vtg + (size_t)((b * 4 + kv) * 128 + r) * 2048 + kb + cc * 8;
      *(bf16x8*)(Vtt + r * 128 + ((cc * 16) ^ ((r & 7) << 4))) = *(const bf16x8*)src;
    }
    __syncthreads();

    // S = Q K^T (wave: 32 q-rows x 64 k-rows)
    f32x4 sa[2][4];
#pragma unroll
    for (int i = 0; i < 2; ++i)
#pragma unroll
      for (int j = 0; j < 4; ++j)
#pragma unroll
        for (int r = 0; r < 4; ++r) sa[i][j][r] = 0.0f;
#pragma unroll
    for (int ks = 0; ks < 4; ++ks) {
      const int kbyte = ks * 64 + lg * 16;
      bf16x8 bk[4];
#pragma unroll
      for (int nf = 0; nf < 4; ++nf) {
        int n = nf * 16 + l15;
        bk[nf] = *(const bf16x8*)(Kt + n * 256 + (kbyte ^ ((n & 7) << 4)));
      }
#pragma unroll
      for (int rf = 0; rf < 2; ++rf)
#pragma unroll
        for (int nf = 0; nf < 4; ++nf)
          sa[rf][nf] = MFMA_BF16(qf[rf][ks], bk[nf], sa[rf][nf]);
    }

    // online softmax (row-wise over 16-lane groups)
    const bool needmask = (kb + 63 > qr);
#pragma unroll
    for (int rf = 0; rf < 2; ++rf)
#pragma unroll
      for (int r = 0; r < 4; ++r) {
        int qi = qr + rf * 16 + lg * 4 + r;
        float mx = -1e30f;
#pragma unroll
        for (int nf = 0; nf < 4; ++nf) {
          float s = sa[rf][nf][r] * scale;
          if (needmask) {
            int ki = kb + nf * 16 + l15;
            if (ki > qi) s = -1e30f;
          }
          sa[rf][nf][r] = s;
          mx = fmaxf(mx, s);
        }
#pragma unroll
        for (int off = 1; off < 16; off <<= 1) mx = fmaxf(mx, __shfl_xor(mx, off));
        float mnew = fmaxf(mrun[rf][r], mx);
        float fac = __builtin_amdgcn_exp2f((mrun[rf][r] - mnew) * L2E);
        float rsum = 0.0f;
#pragma unroll
        for (int nf = 0; nf < 4; ++nf) {
          float pv = __builtin_amdgcn_exp2f((sa[rf][nf][r] - mnew) * L2E);
          sa[rf][nf][r] = pv;
          rsum += pv;
        }
#pragma unroll
        for (int off = 1; off < 16; off <<= 1) rsum += __shfl_xor(rsum, off);
        lrun[rf][r] = lrun[rf][r] * fac + rsum;
        mrun[rf][r] = mnew;
#pragma unroll
        for (int nf2 = 0; nf2 < 8; ++nf2) o[rf][nf2][r] *= fac;
      }

    // P (bf16) -> per-wave LDS, swizzled row-major [32][64]
#pragma unroll
    for (int rf = 0; rf < 2; ++rf)
#pragma unroll
      for (int nf = 0; nf < 4; ++nf)
#pragma unroll
        for (int r = 0; r < 4; ++r) {
          int prow = rf * 16 + lg * 4 + r;
          int colb = (nf * 16 + l15) * 2;
          *(bf16*)(Pl + prow * 128 + (colb ^ ((prow & 7) << 4))) = (bf16)sa[rf][nf][r];
        }

    // O += P V
#pragma unroll
    for (int ks = 0; ks < 2; ++ks) {
      const int kbyte = ks * 64 + lg * 16;
      bf16x8 pa[2];
#pragma unroll
      for (int rf = 0; rf < 2; ++rf) {
        int mr = rf * 16 + l15;
        pa[rf] = *(const bf16x8*)(Pl + mr * 128 + (kbyte ^ ((mr & 7) << 4)));
      }
#pragma unroll
      for (int nf2 = 0; nf2 < 8; ++nf2) {
        int d = nf2 * 16 + l15;
        bf16x8 vb = *(const bf16x8*)(Vtt + d * 128 + (kbyte ^ ((d & 7) << 4)));
#pragma unroll
        for (int rf = 0; rf < 2; ++rf)
          o[rf][nf2] = MFMA_BF16(pa[rf], vb, o[rf][nf2]);
      }
    }
  }

  // epilogue: O /= l, store bf16
#pragma unroll
  for (int rf = 0; rf < 2; ++rf) {
    float inv[4];
#pragma unroll
    for (int r = 0; r < 4; ++r) inv[r] = 1.0f / lrun[rf][r];
#pragma unroll
    for (int nf2 = 0; nf2 < 8; ++nf2)
#pragma unroll
      for (int r = 0; r < 4; ++r) {
        int row = b * 2048 + qr + rf * 16 + lg * 4 + r;
        AO[(size_t)row * 2048 + h * 128 + nf2 * 16 + l15] = (bf16)(o[rf][nf2][r] * inv[r]);
      }
  }
}

// ------------------------------------------------------------------
extern "C" void kernel_launch(void* const* d_in, const int* in_sizes, int n_in,
                              void* d_out, int out_size, void* d_ws, size_t ws_size,
                              hipStream_t stream) {
  const float* hs   = (const float*)d_in[0];
  const float* cosb = (const float*)d_in[1];
  const float* sinb = (const float*)d_in[2];
  const float* Wq   = (const float*)d_in[3];
  const float* Wk   = (const float*)d_in[4];
  const float* Wv   = (const float*)d_in[5];
  const float* Wo   = (const float*)d_in[6];
  float* Out = (float*)d_out;

  char* ws = (char*)d_ws;
  size_t off = 0;
  auto alloc = [&](size_t bytes) { char* p = ws + off; off += bytes; return p; };
  bf16* Xbf = (bf16*)alloc((size_t)4096 * 2048 * 2);
  bf16* Wtq = (bf16*)alloc((size_t)2048 * 2048 * 2);
  bf16* Wtk = (bf16*)alloc((size_t)512 * 2048 * 2);
  bf16* Wtv = (bf16*)alloc((size_t)512 * 2048 * 2);
  bf16* Wto = (bf16*)alloc((size_t)2048 * 2048 * 2);
  bf16* Qb  = (bf16*)alloc((size_t)4096 * 2048 * 2);
  bf16* Kb  = (bf16*)alloc((size_t)4096 * 512 * 2);
  bf16* Vb  = (bf16*)alloc((size_t)4096 * 512 * 2);
  bf16* Vtb = (bf16*)alloc((size_t)4096 * 512 * 2);
  bf16* AO  = (bf16*)alloc((size_t)4096 * 2048 * 2);

  dim3 tb(32, 8);
  k_cvt_bf16<<<8192, 256, 0, stream>>>(hs, Xbf, 2097152);
  k_transpose_w<<<dim3(64, 64), tb, 0, stream>>>(Wq, Wtq, 2048, 2048);
  k_transpose_w<<<dim3(64, 16), tb, 0, stream>>>(Wk, Wtk, 2048, 512);
  k_transpose_w<<<dim3(64, 16), tb, 0, stream>>>(Wv, Wtv, 2048, 512);
  k_transpose_w<<<dim3(64, 64), tb, 0, stream>>>(Wo, Wto, 2048, 2048);
  k_gemm_qkv<<<dim3(32, 24), 256, 0, stream>>>(Xbf, Wtq, Wtk, Wtv, Qb, Kb, Vb);
  k_rope<<<16384, 256, 0, stream>>>(Qb, cosb, sinb, 2048);
  k_rope<<<4096, 256, 0, stream>>>(Kb, cosb, sinb, 512);
  k_transpose_v<<<dim3(64, 16, 2), tb, 0, stream>>>(Vb, Vtb);
  k_fattn<<<dim3(16, 16, 2), 256, 0, stream>>>(Qb, Kb, Vtb, AO);
  k_gemm_o<<<dim3(32, 16), 256, 0, stream>>>(AO, Wto, Out);
}